// Round 1
// baseline (656.023 us; speedup 1.0000x reference)
//
#include <hip/hip_runtime.h>
#include <cstdint>

#define H 2048
#define NH 16
#define QLR 1536
#define KVLR 512
#define NOPE 128
#define ROPED 64
#define VH 128
#define QHD 192
#define SEQ 2048
#define NQH (NH*QHD)        // 3072
#define NKVC (NH*(NOPE+VH)) // 4096
#define NOV (NH*VH)         // 2048
#define KVAW_N (KVLR+ROPED) // 576

typedef __attribute__((ext_vector_type(8))) short short8;
typedef __attribute__((ext_vector_type(4))) short short4v;
typedef __attribute__((ext_vector_type(4))) float floatx4;

__device__ __forceinline__ short f2bf(float x) {
  unsigned u = __builtin_bit_cast(unsigned, x);
  unsigned r = (u + 0x7FFFu + ((u >> 16) & 1u)) >> 16;
  return (short)(unsigned short)r;
}

__device__ __forceinline__ void g2l16(const void* g, void* l) {
  __builtin_amdgcn_global_load_lds(
      (const __attribute__((address_space(1))) void*)(uintptr_t)(g),
      (__attribute__((address_space(3))) void*)(uintptr_t)(l),
      16, 0, 0);
}

// ---------------- fp32 -> bf16 convert ----------------
__global__ __launch_bounds__(256) void k_cvt_bf16(const float* __restrict__ x,
                                                  short* __restrict__ y, int n4) {
  int i = blockIdx.x * 256 + threadIdx.x;
  if (i >= n4) return;
  float4 v = ((const float4*)x)[i];
  short4v o;
  o.x = f2bf(v.x); o.y = f2bf(v.y); o.z = f2bf(v.z); o.w = f2bf(v.w);
  ((short4v*)y)[i] = o;
}

// ---------------- NT GEMM: C[M,N] = A[M,K] * B[N,K]^T (bf16 in, fp32 acc) ----
// 128x128 tile, BK=32, 4 waves in 2x2, 16x16x32 bf16 MFMA, global_load_lds.
template<int WRITE_BF16>
__global__ __launch_bounds__(256) void k_gemm_nt(
    const short* __restrict__ A, const short* __restrict__ B,
    void* __restrict__ C, int M, int N, int K)
{
  __shared__ short As[4*128*8];
  __shared__ short Bs[4*128*8];
  const int tid = threadIdx.x;
  const int lane = tid & 63;
  const int w = tid >> 6;
  const int wm = w & 1, wn = w >> 1;
  const int quad = lane >> 4, l16 = lane & 15;
  const int m0 = blockIdx.x * 128, n0 = blockIdx.y * 128;

  floatx4 acc[4][4] = {};

  for (int k0 = 0; k0 < K; k0 += 32) {
    __syncthreads();
#pragma unroll
    for (int i = 0; i < 2; ++i) {
      int c = i*256 + tid;            // chunk id = koct*128 + row
      int row = c & 127, koct = c >> 7;
      g2l16(A + (size_t)(m0 + row)*K + k0 + koct*8, As + (size_t)(i*256 + w*64)*8);
      int nrow = n0 + row; nrow = (nrow < N) ? nrow : (N-1);
      g2l16(B + (size_t)nrow*K + k0 + koct*8,      Bs + (size_t)(i*256 + w*64)*8);
    }
    __syncthreads();
    short8 af[4], bf[4];
#pragma unroll
    for (int mi = 0; mi < 4; ++mi)
      af[mi] = *(const short8*)(As + (quad*128 + wm*64 + mi*16 + l16)*8);
#pragma unroll
    for (int ni = 0; ni < 4; ++ni)
      bf[ni] = *(const short8*)(Bs + (quad*128 + wn*64 + ni*16 + l16)*8);
#pragma unroll
    for (int mi = 0; mi < 4; ++mi)
#pragma unroll
      for (int ni = 0; ni < 4; ++ni)
        acc[mi][ni] = __builtin_amdgcn_mfma_f32_16x16x32_bf16(af[mi], bf[ni], acc[mi][ni], 0, 0, 0);
  }

#pragma unroll
  for (int mi = 0; mi < 4; ++mi) {
#pragma unroll
    for (int ni = 0; ni < 4; ++ni) {
      int col = n0 + wn*64 + ni*16 + l16;
      if (col < N) {
#pragma unroll
        for (int r = 0; r < 4; ++r) {
          int row = m0 + wm*64 + mi*16 + quad*4 + r;
          if (WRITE_BF16)
            ((short*)C)[(size_t)row*N + col] = f2bf(acc[mi][ni][r]);
          else
            ((float*)C)[(size_t)row*N + col] = acc[mi][ni][r];
        }
      }
    }
  }
}

// ---------------- RMS norm (row-wise, fp32 -> bf16) ----------------
__global__ __launch_bounds__(256) void k_rmsnorm(
    const float* __restrict__ x, int xstride,
    const float* __restrict__ w, short* __restrict__ y, int L)
{
  int row = blockIdx.x;
  const float* xr = x + (size_t)row * xstride;
  float s = 0.f;
  for (int i = threadIdx.x; i < L; i += 256) { float v = xr[i]; s += v*v; }
#pragma unroll
  for (int off = 1; off < 64; off <<= 1) s += __shfl_xor(s, off);
  __shared__ float red[4];
  if ((threadIdx.x & 63) == 0) red[threadIdx.x >> 6] = s;
  __syncthreads();
  float tot = red[0] + red[1] + red[2] + red[3];
  float inv = rsqrtf(tot / (float)L + 1e-6f);
  for (int i = threadIdx.x; i < L; i += 256)
    y[(size_t)row * L + i] = f2bf(xr[i] * inv * w[i]);
}

// ---------------- RoPE on q (+ fp32->bf16 of full q) ----------------
__global__ __launch_bounds__(256) void k_rope_q(const float* __restrict__ q,
                                                short* __restrict__ qb) {
  int row = blockIdx.y;
  int t2 = blockIdx.x * 256 + threadIdx.x;  // 0..2559
  int h = t2 / 160, d = t2 - h * 160;
  const float* src = q + (size_t)row * NQH + h * QHD;
  short* dst = qb + (size_t)row * NQH + h * QHD;
  if (d < 128) {
    dst[d] = f2bf(src[d]);
  } else {
    int i = d - 128;                        // 0..31
    float ang = (float)row * powf(10000.0f, -(float)i / 32.0f);
    float c = cosf(ang), s = sinf(ang);
    float x1 = src[128 + i], x2 = src[160 + i];
    dst[128 + i] = f2bf(x1 * c - x2 * s);
    dst[160 + i] = f2bf(x2 * c + x1 * s);
  }
}

// ---------------- RoPE on k_pe (from kv_lat_pe cols 512..575) ----------------
__global__ __launch_bounds__(256) void k_rope_k(const float* __restrict__ kvlp,
                                                short* __restrict__ kpe) {
  int idx = blockIdx.x * 256 + threadIdx.x;  // SEQ*32
  int row = idx >> 5, i = idx & 31;
  const float* src = kvlp + (size_t)row * KVAW_N + KVLR;
  float ang = (float)row * powf(10000.0f, -(float)i / 32.0f);
  float c = cosf(ang), s = sinf(ang);
  float x1 = src[i], x2 = src[i + 32];
  kpe[(size_t)row * ROPED + i]      = f2bf(x1 * c - x2 * s);
  kpe[(size_t)row * ROPED + i + 32] = f2bf(x2 * c + x1 * s);
}

// ---------------- causal flash attention ----------------
// grid (SEQ/64, NH), block 256 = 4 waves; wave handles 16 q rows, BKV=32.
__global__ __launch_bounds__(256) void k_attn(
    const short* __restrict__ qb,   // [SEQ][NQH]
    const short* __restrict__ kvb,  // [SEQ][NKVC]
    const short* __restrict__ kpe,  // [SEQ][ROPED]
    short* __restrict__ ob)         // [SEQ][NOV]
{
  __shared__ short Kl[32 * 200];    // [kv=32][dim 192 pad 200]
  __shared__ short Vl[128 * 40];    // V^T: [vd=128][kv 32 pad 40]
  __shared__ short Pl[4 * 16 * 40]; // per wave [q=16][kv 32 pad 40]
  const int tid = threadIdx.x;
  const int lane = tid & 63, w = tid >> 6;
  const int quad = lane >> 4, l16 = lane & 15;
  const int h = blockIdx.y, qt = blockIdx.x;
  const int q0 = qt * 64;
  const int qrow = q0 + w * 16 + l16;

  short8 qf[6];
#pragma unroll
  for (int ks = 0; ks < 6; ++ks)
    qf[ks] = *(const short8*)(qb + (size_t)qrow * NQH + h * QHD + ks * 32 + quad * 8);

  floatx4 o[8] = {};
  float m_i[4], l_i[4];
#pragma unroll
  for (int r = 0; r < 4; ++r) { m_i[r] = -1e30f; l_i[r] = 0.f; }

  const float scale = 0.07216878364870323f;   // 192^-0.5
  const int nkv = q0 / 32 + 2;
  for (int kc = 0; kc < nkv; ++kc) {
    const int kv0 = kc * 32;
    __syncthreads();
    // stage K: 32 rows x 24 octets (16 nope + 8 rope)
    for (int c = tid; c < 768; c += 256) {
      int row = c / 24, oct = c - row * 24;
      const short* src = (oct < 16)
          ? kvb + (size_t)(kv0 + row) * NKVC + h * 256 + oct * 8
          : kpe + (size_t)(kv0 + row) * ROPED + (oct - 16) * 8;
      *(short8*)(Kl + row * 200 + oct * 8) = *(const short8*)src;
    }
    // stage V transposed (conflict-free scalar writes: lanes span consecutive kv)
    for (int c = tid; c < 512; c += 256) {
      int row = (c & 15) + ((c >> 8) << 4);
      int oc = (c >> 4) & 15;
      short8 v = *(const short8*)(kvb + (size_t)(kv0 + row) * NKVC + h * 256 + 128 + oc * 8);
#pragma unroll
      for (int j = 0; j < 8; ++j) Vl[(oc * 8 + j) * 40 + row] = v[j];
    }
    __syncthreads();
    // S = Q K^T
    floatx4 sacc[2] = {};
#pragma unroll
    for (int ks = 0; ks < 6; ++ks) {
#pragma unroll
      for (int n = 0; n < 2; ++n) {
        short8 kf = *(const short8*)(Kl + (n * 16 + l16) * 200 + ks * 32 + quad * 8);
        sacc[n] = __builtin_amdgcn_mfma_f32_16x16x32_bf16(qf[ks], kf, sacc[n], 0, 0, 0);
      }
    }
    // online softmax (C layout: row = quad*4+r, col = n*16+l16)
    float pv[2][4], mx[4];
    const int rowg = q0 + w * 16 + quad * 4;
#pragma unroll
    for (int r = 0; r < 4; ++r) mx[r] = -1e30f;
#pragma unroll
    for (int n = 0; n < 2; ++n) {
      int colg = kv0 + n * 16 + l16;
#pragma unroll
      for (int r = 0; r < 4; ++r) {
        float val = sacc[n][r] * scale;
        val = (colg <= rowg + r) ? val : -1e30f;
        pv[n][r] = val;
        mx[r] = fmaxf(mx[r], val);
      }
    }
#pragma unroll
    for (int off = 1; off < 16; off <<= 1)
#pragma unroll
      for (int r = 0; r < 4; ++r) mx[r] = fmaxf(mx[r], __shfl_xor(mx[r], off));
    float al[4], rs[4];
#pragma unroll
    for (int r = 0; r < 4; ++r) {
      float mn = fmaxf(m_i[r], mx[r]);
      al[r] = __expf(m_i[r] - mn);
      m_i[r] = mn;
    }
#pragma unroll
    for (int r = 0; r < 4; ++r) {
      pv[0][r] = __expf(pv[0][r] - m_i[r]);
      pv[1][r] = __expf(pv[1][r] - m_i[r]);
      rs[r] = pv[0][r] + pv[1][r];
    }
#pragma unroll
    for (int off = 1; off < 16; off <<= 1)
#pragma unroll
      for (int r = 0; r < 4; ++r) rs[r] += __shfl_xor(rs[r], off);
#pragma unroll
    for (int r = 0; r < 4; ++r) l_i[r] = l_i[r] * al[r] + rs[r];
#pragma unroll
    for (int vn = 0; vn < 8; ++vn)
#pragma unroll
      for (int r = 0; r < 4; ++r) o[vn][r] *= al[r];
    // P: C layout -> LDS -> A layout
#pragma unroll
    for (int n = 0; n < 2; ++n)
#pragma unroll
      for (int r = 0; r < 4; ++r)
        Pl[w * 640 + (quad * 4 + r) * 40 + n * 16 + l16] = f2bf(pv[n][r]);
    __syncthreads();
    short8 pa = *(const short8*)(Pl + w * 640 + l16 * 40 + quad * 8);
#pragma unroll
    for (int vn = 0; vn < 8; ++vn) {
      short8 vf = *(const short8*)(Vl + (vn * 16 + l16) * 40 + quad * 8);
      o[vn] = __builtin_amdgcn_mfma_f32_16x16x32_bf16(pa, vf, o[vn], 0, 0, 0);
    }
  }
#pragma unroll
  for (int r = 0; r < 4; ++r) {
    float inv = 1.f / l_i[r];
    int row = q0 + w * 16 + quad * 4 + r;
#pragma unroll
    for (int vn = 0; vn < 8; ++vn)
      ob[(size_t)row * NOV + h * VH + vn * 16 + l16] = f2bf(o[vn][r] * inv);
  }
}

// ---------------- launch ----------------
extern "C" void kernel_launch(void* const* d_in, const int* in_sizes, int n_in,
                              void* d_out, int out_size, void* d_ws, size_t ws_size,
                              hipStream_t stream) {
  const float* hs      = (const float*)d_in[0];
  const float* q_a_w   = (const float*)d_in[1];
  const float* q_a_ln  = (const float*)d_in[2];
  const float* q_b_w   = (const float*)d_in[3];
  const float* kv_a_w  = (const float*)d_in[4];
  const float* kv_a_ln = (const float*)d_in[5];
  const float* kv_b_w  = (const float*)d_in[6];
  const float* o_w     = (const float*)d_in[7];
  float* out = (float*)d_out;

  char* ws = (char*)d_ws;
  size_t off = 0;
  auto alloc = [&](size_t bytes) {
    void* p = ws + off;
    off += (bytes + 255) & ~(size_t)255;
    return p;
  };
  short* hs_b   = (short*)alloc((size_t)SEQ * H * 2);
  short* qaw_b  = (short*)alloc((size_t)QLR * H * 2);
  short* qbw_b  = (short*)alloc((size_t)NQH * QLR * 2);
  short* kvaw_b = (short*)alloc((size_t)KVAW_N * H * 2);
  short* kvbw_b = (short*)alloc((size_t)NKVC * KVLR * 2);
  short* ow_b   = (short*)alloc((size_t)H * NOV * 2);
  float* qlat   = (float*)alloc((size_t)SEQ * QLR * 4);
  short* qlatn  = (short*)alloc((size_t)SEQ * QLR * 2);
  float* qf32   = (float*)alloc((size_t)SEQ * NQH * 4);
  short* qbf    = (short*)alloc((size_t)SEQ * NQH * 2);
  float* kvlp   = (float*)alloc((size_t)SEQ * KVAW_N * 4);
  short* kvln   = (short*)alloc((size_t)SEQ * KVLR * 2);
  short* kpeb   = (short*)alloc((size_t)SEQ * ROPED * 2);
  short* kvbuf  = (short*)alloc((size_t)SEQ * NKVC * 2);
  short* attnb  = (short*)alloc((size_t)SEQ * NOV * 2);

  auto cvt = [&](const float* x, short* y, size_t n) {
    int n4 = (int)(n / 4);
    k_cvt_bf16<<<dim3((n4 + 255) / 256), 256, 0, stream>>>(x, y, n4);
  };
  cvt(hs,     hs_b,   (size_t)SEQ * H);
  cvt(q_a_w,  qaw_b,  (size_t)QLR * H);
  cvt(q_b_w,  qbw_b,  (size_t)NQH * QLR);
  cvt(kv_a_w, kvaw_b, (size_t)KVAW_N * H);
  cvt(kv_b_w, kvbw_b, (size_t)NKVC * KVLR);
  cvt(o_w,    ow_b,   (size_t)H * NOV);

  // q_lat = hs @ q_a_w^T          [2048,1536] fp32
  k_gemm_nt<0><<<dim3(SEQ/128, QLR/128), 256, 0, stream>>>(hs_b, qaw_b, qlat, SEQ, QLR, H);
  // rmsnorm(q_lat) -> bf16
  k_rmsnorm<<<SEQ, 256, 0, stream>>>(qlat, QLR, q_a_ln, qlatn, QLR);
  // q = q_lat_n @ q_b_w^T         [2048,3072] fp32
  k_gemm_nt<0><<<dim3(SEQ/128, NQH/128), 256, 0, stream>>>(qlatn, qbw_b, qf32, SEQ, NQH, QLR);
  // rope(q_pe) + convert q -> bf16
  k_rope_q<<<dim3(10, SEQ), 256, 0, stream>>>(qf32, qbf);
  // kv_lat_pe = hs @ kv_a_w^T     [2048,576] fp32
  k_gemm_nt<0><<<dim3(SEQ/128, (KVAW_N+127)/128), 256, 0, stream>>>(hs_b, kvaw_b, kvlp, SEQ, KVAW_N, H);
  // rmsnorm(kv_lat) -> bf16
  k_rmsnorm<<<SEQ, 256, 0, stream>>>(kvlp, KVAW_N, kv_a_ln, kvln, KVLR);
  // rope(k_pe) -> bf16
  k_rope_k<<<(SEQ*32)/256, 256, 0, stream>>>(kvlp, kpeb);
  // kv = kv_lat_n @ kv_b_w^T      [2048,4096] bf16
  k_gemm_nt<1><<<dim3(SEQ/128, NKVC/128), 256, 0, stream>>>(kvln, kvbw_b, kvbuf, SEQ, NKVC, KVLR);
  // attention
  k_attn<<<dim3(SEQ/64, NH), 256, 0, stream>>>(qbf, kvbuf, kpeb, attnb);
  // out = attn @ o_w^T            [2048,2048] fp32
  k_gemm_nt<0><<<dim3(SEQ/128, H/128), 256, 0, stream>>>(attnb, ow_b, out, SEQ, H, NOV);
}

// Round 2
// 546.219 us; speedup vs baseline: 1.2010x; 1.2010x over previous
//
#include <hip/hip_runtime.h>
#include <cstdint>

#define H 2048
#define NH 16
#define QLR 1536
#define KVLR 512
#define NOPE 128
#define ROPED 64
#define VH 128
#define QHD 192
#define SEQ 2048
#define NQH (NH*QHD)        // 3072
#define NKVC (NH*(NOPE+VH)) // 4096
#define NOV (NH*VH)         // 2048
#define KVAW_N (KVLR+ROPED) // 576
#define SCALE_L2E 0.10411755f   // 192^-0.5 * log2(e)

typedef __attribute__((ext_vector_type(8))) short short8;
typedef __attribute__((ext_vector_type(4))) short short4v;
typedef __attribute__((ext_vector_type(4))) float floatx4;

__device__ __forceinline__ short f2bf(float x) {
  unsigned u = __builtin_bit_cast(unsigned, x);
  unsigned r = (u + 0x7FFFu + ((u >> 16) & 1u)) >> 16;
  return (short)(unsigned short)r;
}
__device__ __forceinline__ float bf2f(short s) {
  unsigned u = ((unsigned)(unsigned short)s) << 16;
  return __builtin_bit_cast(float, u);
}
__device__ __forceinline__ void g2l16(const void* g, void* l) {
  __builtin_amdgcn_global_load_lds(
      (const __attribute__((address_space(1))) void*)(uintptr_t)(g),
      (__attribute__((address_space(3))) void*)(uintptr_t)(l),
      16, 0, 0);
}

// ---------------- fp32 -> bf16 convert ----------------
__global__ __launch_bounds__(256) void k_cvt_bf16(const float* __restrict__ x,
                                                  short* __restrict__ y, int n4) {
  int i = blockIdx.x * 256 + threadIdx.x;
  if (i >= n4) return;
  float4 v = ((const float4*)x)[i];
  short4v o;
  o.x = f2bf(v.x); o.y = f2bf(v.y); o.z = f2bf(v.z); o.w = f2bf(v.w);
  ((short4v*)y)[i] = o;
}

// ---------------- NT GEMM: C[M,N] = A[M,K]*B[N,K]^T ----------------
// MODE 0: fp32 out. MODE 1: bf16 out. MODE 2: kv-special (K half -> bf16 C,
// V half -> transposed bf16 C2 as vT[h*128+d][seq], packed 8B stores).
template<int MODE>
__global__ __launch_bounds__(256) void k_gemm_nt(
    const short* __restrict__ A, const short* __restrict__ B,
    void* __restrict__ C, short* __restrict__ C2, int M, int N, int K)
{
  __shared__ short As[4*128*8];
  __shared__ short Bs[4*128*8];
  const int tid = threadIdx.x;
  const int lane = tid & 63;
  const int w = tid >> 6;
  const int wm = w & 1, wn = w >> 1;
  const int quad = lane >> 4, l16 = lane & 15;
  const int m0 = blockIdx.x * 128, n0 = blockIdx.y * 128;

  floatx4 acc[4][4] = {};

  for (int k0 = 0; k0 < K; k0 += 32) {
    __syncthreads();
#pragma unroll
    for (int i = 0; i < 2; ++i) {
      int c = i*256 + tid;
      int row = c & 127, koct = c >> 7;
      g2l16(A + (size_t)(m0 + row)*K + k0 + koct*8, As + (size_t)(i*256 + w*64)*8);
      int nrow = n0 + row; nrow = (nrow < N) ? nrow : (N-1);
      g2l16(B + (size_t)nrow*K + k0 + koct*8,      Bs + (size_t)(i*256 + w*64)*8);
    }
    __syncthreads();
    short8 af[4], bfr[4];
#pragma unroll
    for (int mi = 0; mi < 4; ++mi)
      af[mi] = *(const short8*)(As + (quad*128 + wm*64 + mi*16 + l16)*8);
#pragma unroll
    for (int ni = 0; ni < 4; ++ni)
      bfr[ni] = *(const short8*)(Bs + (quad*128 + wn*64 + ni*16 + l16)*8);
#pragma unroll
    for (int mi = 0; mi < 4; ++mi)
#pragma unroll
      for (int ni = 0; ni < 4; ++ni)
        acc[mi][ni] = __builtin_amdgcn_mfma_f32_16x16x32_bf16(af[mi], bfr[ni], acc[mi][ni], 0, 0, 0);
  }

  if (MODE == 2 && (n0 & 128)) {
    // V half: write transposed vT[(h*128+d)][row], 4 rows packed per store
#pragma unroll
    for (int mi = 0; mi < 4; ++mi) {
#pragma unroll
      for (int ni = 0; ni < 4; ++ni) {
        int col = n0 + wn*64 + ni*16 + l16;
        int h = col >> 8, dv = (col & 255) - 128;
        int row = m0 + wm*64 + mi*16 + quad*4;
        short4v pk;
        pk.x = f2bf(acc[mi][ni][0]); pk.y = f2bf(acc[mi][ni][1]);
        pk.z = f2bf(acc[mi][ni][2]); pk.w = f2bf(acc[mi][ni][3]);
        *(short4v*)(C2 + (size_t)(h*128 + dv)*SEQ + row) = pk;
      }
    }
    return;
  }

#pragma unroll
  for (int mi = 0; mi < 4; ++mi) {
#pragma unroll
    for (int ni = 0; ni < 4; ++ni) {
      int col = n0 + wn*64 + ni*16 + l16;
      if (col < N) {
#pragma unroll
        for (int r = 0; r < 4; ++r) {
          int row = m0 + wm*64 + mi*16 + quad*4 + r;
          if (MODE == 0)
            ((float*)C)[(size_t)row*N + col] = acc[mi][ni][r];
          else
            ((short*)C)[(size_t)row*N + col] = f2bf(acc[mi][ni][r]);
        }
      }
    }
  }
}

// ---------------- RMS norm (row-wise, fp32 -> bf16) ----------------
__global__ __launch_bounds__(256) void k_rmsnorm(
    const float* __restrict__ x, int xstride,
    const float* __restrict__ w, short* __restrict__ y, int L)
{
  int row = blockIdx.x;
  const float* xr = x + (size_t)row * xstride;
  float s = 0.f;
  for (int i = threadIdx.x; i < L; i += 256) { float v = xr[i]; s += v*v; }
#pragma unroll
  for (int off = 1; off < 64; off <<= 1) s += __shfl_xor(s, off);
  __shared__ float red[4];
  if ((threadIdx.x & 63) == 0) red[threadIdx.x >> 6] = s;
  __syncthreads();
  float tot = red[0] + red[1] + red[2] + red[3];
  float inv = rsqrtf(tot / (float)L + 1e-6f);
  for (int i = threadIdx.x; i < L; i += 256)
    y[(size_t)row * L + i] = f2bf(xr[i] * inv * w[i]);
}

// ---------------- RoPE+prescale on q (bf16 in -> bf16 out) ----------------
__global__ __launch_bounds__(256) void k_rope_q(const short* __restrict__ q,
                                                short* __restrict__ qb) {
  int row = blockIdx.y;
  int t2 = blockIdx.x * 256 + threadIdx.x;  // 0..2559
  int h = t2 / 160, d = t2 - h * 160;
  const short* src = q + (size_t)row * NQH + h * QHD;
  short* dst = qb + (size_t)row * NQH + h * QHD;
  if (d < 128) {
    dst[d] = f2bf(bf2f(src[d]) * SCALE_L2E);
  } else {
    int i = d - 128;                        // 0..31
    float ang = (float)row * powf(10000.0f, -(float)i / 32.0f);
    float c = cosf(ang), s = sinf(ang);
    float x1 = bf2f(src[128 + i]), x2 = bf2f(src[160 + i]);
    dst[128 + i] = f2bf((x1 * c - x2 * s) * SCALE_L2E);
    dst[160 + i] = f2bf((x2 * c + x1 * s) * SCALE_L2E);
  }
}

// ---------------- RoPE on k_pe (fp32 in, NOT scaled) ----------------
__global__ __launch_bounds__(256) void k_rope_k(const float* __restrict__ kvlp,
                                                short* __restrict__ kpe) {
  int idx = blockIdx.x * 256 + threadIdx.x;  // SEQ*32
  int row = idx >> 5, i = idx & 31;
  const float* src = kvlp + (size_t)row * KVAW_N + KVLR;
  float ang = (float)row * powf(10000.0f, -(float)i / 32.0f);
  float c = cosf(ang), s = sinf(ang);
  float x1 = src[i], x2 = src[i + 32];
  kpe[(size_t)row * ROPED + i]      = f2bf(x1 * c - x2 * s);
  kpe[(size_t)row * ROPED + i + 32] = f2bf(x2 * c + x1 * s);
}

// ---------------- causal flash attention, S^T formulation ----------------
// grid (32, NH) block 128 (2 waves). Wave owns 32 q rows; BKV=64.
// S^T = K*Q^T (C-layout: col=q on l16, row=kv on quad*4+r)
// O^T = V^T * P^T : A=V^T[d][kv], B=P[q][kv] via wave-private LDS transpose.
__global__ __launch_bounds__(128) void k_attn2(
    const short* __restrict__ qb,   // [SEQ][NQH] prescaled
    const short* __restrict__ kvb,  // [SEQ][NKVC] (K-nope half valid)
    const short* __restrict__ kpe,  // [SEQ][ROPED]
    const short* __restrict__ vT,   // [NH*128][SEQ]
    short* __restrict__ ob)         // [SEQ][NOV]
{
  __shared__ short Kl[64 * 200];    // [kv 64][dim 192 pad 200]
  __shared__ short Vl[128 * 72];    // [d 128][kv 64 pad 72]
  __shared__ short Pl[2 * 32 * 72]; // per wave [q 32][kv 64 pad 72]
  const int tid = threadIdx.x;
  const int lane = tid & 63, w = tid >> 6;
  const int quad = lane >> 4, l16 = lane & 15;
  const int h = blockIdx.y;
  const int qt = (int)(gridDim.x - 1) - blockIdx.x;  // long blocks first
  const int q0 = qt * 64;
  const int qw = q0 + w * 32;
  short* Plw = Pl + w * (32 * 72);

  // Q B-frags: [nt][ks]
  short8 qf[2][6];
#pragma unroll
  for (int nt = 0; nt < 2; ++nt)
#pragma unroll
    for (int ks = 0; ks < 6; ++ks)
      qf[nt][ks] = *(const short8*)(qb + (size_t)(qw + nt*16 + l16) * NQH
                                    + h * QHD + ks * 32 + quad * 8);

  floatx4 oacc[8][2] = {};   // [dt][nt]  row=d, col=q
  float m_i[2] = {-1e30f, -1e30f}, l_i[2] = {0.f, 0.f};

  const int nch = qt + 1;
  for (int kc = 0; kc < nch; ++kc) {
    const int kv0 = kc * 64;
    __syncthreads();
    // stage K-nope: 64 rows x 16 octets
#pragma unroll
    for (int i = 0; i < 8; ++i) {
      int c = i * 128 + tid;
      int row = c >> 4, oct = c & 15;
      *(short8*)(Kl + row * 200 + oct * 8) =
          *(const short8*)(kvb + (size_t)(kv0 + row) * NKVC + h * 256 + oct * 8);
    }
    // stage K-rope: 64 rows x 8 octets
#pragma unroll
    for (int i = 0; i < 4; ++i) {
      int c = i * 128 + tid;
      int row = c >> 3, oct = c & 7;
      *(short8*)(Kl + row * 200 + 128 + oct * 8) =
          *(const short8*)(kpe + (size_t)(kv0 + row) * ROPED + oct * 8);
    }
    // stage V^T: 128 d rows x 8 kv-octets
#pragma unroll
    for (int i = 0; i < 8; ++i) {
      int c = i * 128 + tid;
      int d = c >> 3, ck = c & 7;
      *(short8*)(Vl + d * 72 + ck * 8) =
          *(const short8*)(vT + (size_t)(h * 128 + d) * SEQ + kv0 + ck * 8);
    }
    __syncthreads();

    // S^T tiles [mt][nt]
    floatx4 s[4][2] = {};
#pragma unroll
    for (int ks = 0; ks < 6; ++ks) {
#pragma unroll
      for (int mt = 0; mt < 4; ++mt) {
        short8 kf = *(const short8*)(Kl + (mt*16 + l16) * 200 + ks * 32 + quad * 8);
#pragma unroll
        for (int nt = 0; nt < 2; ++nt)
          s[mt][nt] = __builtin_amdgcn_mfma_f32_16x16x32_bf16(kf, qf[nt][ks], s[mt][nt], 0, 0, 0);
      }
    }

    const bool diag = (kc == qt);
#pragma unroll
    for (int nt = 0; nt < 2; ++nt) {
      const int qg = qw + nt * 16 + l16;
      float mx = -1e30f;
#pragma unroll
      for (int mt = 0; mt < 4; ++mt) {
#pragma unroll
        for (int r = 0; r < 4; ++r) {
          float v = s[mt][nt][r];
          if (diag) {
            int kvg = kv0 + mt * 16 + quad * 4 + r;
            v = (kvg <= qg) ? v : -1e30f;
            s[mt][nt][r] = v;
          }
          mx = fmaxf(mx, v);
        }
      }
      mx = fmaxf(mx, __shfl_xor(mx, 16));
      mx = fmaxf(mx, __shfl_xor(mx, 32));
      float mnew = fmaxf(m_i[nt], mx);
      float alpha = exp2f(m_i[nt] - mnew);
      m_i[nt] = mnew;
      float ssum = 0.f;
#pragma unroll
      for (int mt = 0; mt < 4; ++mt) {
        float p0 = exp2f(s[mt][nt][0] - mnew);
        float p1 = exp2f(s[mt][nt][1] - mnew);
        float p2 = exp2f(s[mt][nt][2] - mnew);
        float p3 = exp2f(s[mt][nt][3] - mnew);
        ssum += (p0 + p1) + (p2 + p3);
        short4v pk; pk.x = f2bf(p0); pk.y = f2bf(p1); pk.z = f2bf(p2); pk.w = f2bf(p3);
        *(short4v*)(Plw + (nt*16 + l16) * 72 + mt * 16 + quad * 4) = pk;
      }
      ssum += __shfl_xor(ssum, 16);
      ssum += __shfl_xor(ssum, 32);
      l_i[nt] = l_i[nt] * alpha + ssum;
#pragma unroll
      for (int dt = 0; dt < 8; ++dt)
#pragma unroll
        for (int r = 0; r < 4; ++r) oacc[dt][nt][r] *= alpha;
    }

    // O^T += V^T * P^T
#pragma unroll
    for (int kc2 = 0; kc2 < 2; ++kc2) {
      short8 pf[2];
#pragma unroll
      for (int nt = 0; nt < 2; ++nt)
        pf[nt] = *(const short8*)(Plw + (nt*16 + l16) * 72 + kc2 * 32 + quad * 8);
#pragma unroll
      for (int dt = 0; dt < 8; ++dt) {
        short8 vf = *(const short8*)(Vl + (dt*16 + l16) * 72 + kc2 * 32 + quad * 8);
#pragma unroll
        for (int nt = 0; nt < 2; ++nt)
          oacc[dt][nt] = __builtin_amdgcn_mfma_f32_16x16x32_bf16(vf, pf[nt], oacc[dt][nt], 0, 0, 0);
      }
    }
  }

  // epilogue: O^T C-layout -> ob[q][h*128+d], 4 d packed
#pragma unroll
  for (int nt = 0; nt < 2; ++nt) {
    float inv = 1.f / l_i[nt];
    int q = qw + nt * 16 + l16;
#pragma unroll
    for (int dt = 0; dt < 8; ++dt) {
      short4v pk;
      pk.x = f2bf(oacc[dt][nt][0] * inv);
      pk.y = f2bf(oacc[dt][nt][1] * inv);
      pk.z = f2bf(oacc[dt][nt][2] * inv);
      pk.w = f2bf(oacc[dt][nt][3] * inv);
      *(short4v*)(ob + (size_t)q * NOV + h * VH + dt * 16 + quad * 4) = pk;
    }
  }
}

// ---------------- launch ----------------
extern "C" void kernel_launch(void* const* d_in, const int* in_sizes, int n_in,
                              void* d_out, int out_size, void* d_ws, size_t ws_size,
                              hipStream_t stream) {
  const float* hs      = (const float*)d_in[0];
  const float* q_a_w   = (const float*)d_in[1];
  const float* q_a_ln  = (const float*)d_in[2];
  const float* q_b_w   = (const float*)d_in[3];
  const float* kv_a_w  = (const float*)d_in[4];
  const float* kv_a_ln = (const float*)d_in[5];
  const float* kv_b_w  = (const float*)d_in[6];
  const float* o_w     = (const float*)d_in[7];
  float* out = (float*)d_out;

  char* ws = (char*)d_ws;
  size_t off = 0;
  auto alloc = [&](size_t bytes) {
    void* p = ws + off;
    off += (bytes + 255) & ~(size_t)255;
    return p;
  };
  short* hs_b   = (short*)alloc((size_t)SEQ * H * 2);
  short* qaw_b  = (short*)alloc((size_t)QLR * H * 2);
  short* qbw_b  = (short*)alloc((size_t)NQH * QLR * 2);
  short* kvaw_b = (short*)alloc((size_t)KVAW_N * H * 2);
  short* kvbw_b = (short*)alloc((size_t)NKVC * KVLR * 2);
  short* ow_b   = (short*)alloc((size_t)H * NOV * 2);
  float* qlat   = (float*)alloc((size_t)SEQ * QLR * 4);
  short* qlatn  = (short*)alloc((size_t)SEQ * QLR * 2);
  short* qtmp   = (short*)alloc((size_t)SEQ * NQH * 2);
  short* qbf    = (short*)alloc((size_t)SEQ * NQH * 2);
  float* kvlp   = (float*)alloc((size_t)SEQ * KVAW_N * 4);
  short* kvln   = (short*)alloc((size_t)SEQ * KVLR * 2);
  short* kpeb   = (short*)alloc((size_t)SEQ * ROPED * 2);
  short* kvbuf  = (short*)alloc((size_t)SEQ * NKVC * 2);
  short* vT     = (short*)alloc((size_t)NH * VH * SEQ * 2);
  short* attnb  = (short*)alloc((size_t)SEQ * NOV * 2);

  auto cvt = [&](const float* x, short* y, size_t n) {
    int n4 = (int)(n / 4);
    k_cvt_bf16<<<dim3((n4 + 255) / 256), 256, 0, stream>>>(x, y, n4);
  };
  cvt(hs,     hs_b,   (size_t)SEQ * H);
  cvt(q_a_w,  qaw_b,  (size_t)QLR * H);
  cvt(q_b_w,  qbw_b,  (size_t)NQH * QLR);
  cvt(kv_a_w, kvaw_b, (size_t)KVAW_N * H);
  cvt(kv_b_w, kvbw_b, (size_t)NKVC * KVLR);
  cvt(o_w,    ow_b,   (size_t)H * NOV);

  // q_lat = hs @ q_a_w^T (fp32 out for rmsnorm)
  k_gemm_nt<0><<<dim3(SEQ/128, QLR/128), 256, 0, stream>>>(hs_b, qaw_b, qlat, nullptr, SEQ, QLR, H);
  k_rmsnorm<<<SEQ, 256, 0, stream>>>(qlat, QLR, q_a_ln, qlatn, QLR);
  // q = q_lat_n @ q_b_w^T (bf16 out)
  k_gemm_nt<1><<<dim3(SEQ/128, NQH/128), 256, 0, stream>>>(qlatn, qbw_b, qtmp, nullptr, SEQ, NQH, QLR);
  k_rope_q<<<dim3(10, SEQ), 256, 0, stream>>>(qtmp, qbf);
  // kv_lat_pe = hs @ kv_a_w^T (fp32)
  k_gemm_nt<0><<<dim3(SEQ/128, (KVAW_N+127)/128), 256, 0, stream>>>(hs_b, kvaw_b, kvlp, nullptr, SEQ, KVAW_N, H);
  k_rmsnorm<<<SEQ, 256, 0, stream>>>(kvlp, KVAW_N, kv_a_ln, kvln, KVLR);
  k_rope_k<<<(SEQ*32)/256, 256, 0, stream>>>(kvlp, kpeb);
  // kv = kv_lat_n @ kv_b_w^T : K half -> kvbuf, V half -> vT (transposed)
  k_gemm_nt<2><<<dim3(SEQ/128, NKVC/128), 256, 0, stream>>>(kvln, kvbw_b, kvbuf, vT, SEQ, NKVC, KVLR);
  // attention
  k_attn2<<<dim3(32, NH), 128, 0, stream>>>(qbf, kvbuf, kpeb, vT, attnb);
  // out = attn @ o_w^T (fp32)
  k_gemm_nt<0><<<dim3(SEQ/128, H/128), 256, 0, stream>>>(attnb, ow_b, out, nullptr, SEQ, H, NOV);
}